// Round 10
// baseline (45.383 us; speedup 1.0000x reference)
//
#include <hip/hip_runtime.h>

// DGT forward, collapsed to a binary-tree descent on sign(pred_z[node]).
// Structure: 8-lane groups (8 samples/wave), f32 fast-path dot with 3-step
// DPP group reduce; rare f64 recompute when |z_f32| < EPS_TIE (the only
// region where the f32 sign can disagree with the f64 numpy reference).
//
// Hard-learned laws (R1..R9):
//  - Achieved waves/EU = floor(192 / VGPR) on this setup (fits R1/R3/R5/R6/
//    R8/R9 exactly). The 2nd __launch_bounds__ arg only sets the VGPR cap
//    (256/N); it does NOT pin occupancy (R9 falsified that).
//  - dur ~ 1/(chains-in-flight/SIMD): 12 chains=54us (R3), 16=37-39 (R1/R8).
//  - This round: W-row loads in TWO chunks of 4xfloat4 (peak W regs 16 not
//    32) -> footprint ~62; hint (256,4) caps at 64 -> VGPR<=64 ->
//    3 waves/EU x 8 samples = 24 chains/SIMD.
//  - Spill signature to watch: WRITE_SIZE must stay 8.2MB (pure output).
//  - ALL per-thread state in NAMED float4s (runtime-indexed arrays spill).
//
// Shapes: x [65536,256] f32, W_pred [1023,256], b_pred [1023],
//         W_or [16,1024], action_stds [16,1024].
// d_out = [out (65536x16) | std (65536x16)] f32.

#define BATCH   65536
#define IN_DIM  256
#define NLEVEL  10
#define NLEAF   1024
#define OUT_DIM 16
#define EPS_TIE 1e-3f

#define DPP_QUAD_XOR1   0xB1   // quad_perm [1,0,3,2]  : lane ^1
#define DPP_QUAD_XOR2   0x4E   // quad_perm [2,3,0,1]  : lane ^2
#define DPP_HALF_MIRROR 0x141  // row_half_mirror      : lane l <-> 7-l

template <int CTRL>
__device__ __forceinline__ float dpp_xfer(float v) {
    return __int_as_float(__builtin_amdgcn_update_dpp(
        0, __float_as_int(v), CTRL, 0xf, 0xf, true));
}

// Sum across the 8-lane group; bitwise-identical on all 8 lanes
// (involution pairing + commutative add at every step).
__device__ __forceinline__ float group8_sum(float v) {
    v += dpp_xfer<DPP_QUAD_XOR1>(v);
    v += dpp_xfer<DPP_QUAD_XOR2>(v);
    v += dpp_xfer<DPP_HALF_MIRROR>(v);
    return v;
}
__device__ __forceinline__ float group8_max(float v) {
    v = fmaxf(v, dpp_xfer<DPP_QUAD_XOR1>(v));
    v = fmaxf(v, dpp_xfer<DPP_QUAD_XOR2>(v));
    v = fmaxf(v, dpp_xfer<DPP_HALF_MIRROR>(v));
    return v;
}

// Rare exact-sign fallback (|z_f32| < EPS_TIE). Group-uniform entry: z is
// bitwise-uniform across the 8-lane group, so shuffle partners are active.
// W reloaded ONE float4 at a time to keep cold-path register peak low.
__device__ __forceinline__ int tree_sign_f64(
    float4 x0, float4 x1, float4 x2, float4 x3,
    float4 x4, float4 x5, float4 x6, float4 x7,
    const float* wrow, float bias, int l)
{
    double A0 = 0.0, A1 = 0.0, A2 = 0.0, A3 = 0.0;
#define ACC64(K, XV)                                                        \
    {                                                                       \
        float4 w = *reinterpret_cast<const float4*>(wrow + (K)*32 + l * 4); \
        A0 += (double)XV.x * (double)w.x; A1 += (double)XV.y * (double)w.y; \
        A2 += (double)XV.z * (double)w.z; A3 += (double)XV.w * (double)w.w; \
    }
    ACC64(0, x0) ACC64(1, x1) ACC64(2, x2) ACC64(3, x3)
    ACC64(4, x4) ACC64(5, x5) ACC64(6, x6) ACC64(7, x7)
#undef ACC64
    double Z = (A0 + A1) + (A2 + A3);
    #pragma unroll
    for (int off = 4; off > 0; off >>= 1)   // xor involution: uniform result
        Z += __shfl_xor(Z, off, 64);
    Z += (double)bias;
    return (Z < 0.0) ? 1 : 0;
}

// 256 threads = 4 waves; 8 samples/wave -> 32/block, 2048 blocks.
__global__ __launch_bounds__(256, 4) void dgt_kernel(
    const float* __restrict__ x,
    const float* __restrict__ W_pred,
    const float* __restrict__ b_pred,
    const float* __restrict__ W_or,
    const float* __restrict__ a_std,
    float* __restrict__ out)
{
    const int lane = threadIdx.x & 63;
    const int wid  = threadIdx.x >> 6;   // wave in block (0..3)
    const int l    = lane & 7;           // lane within 8-group
    const int g    = lane >> 3;          // group (sample) within wave
    const int sample = blockIdx.x * 32 + wid * 8 + g;

    // x fragment: elem k*32 + l*4 + c; 128B coalesced segments per group.
    const float* xrow = x + (size_t)sample * IN_DIM;
    float4 x0 = *reinterpret_cast<const float4*>(xrow +   0 + l * 4);
    float4 x1 = *reinterpret_cast<const float4*>(xrow +  32 + l * 4);
    float4 x2 = *reinterpret_cast<const float4*>(xrow +  64 + l * 4);
    float4 x3 = *reinterpret_cast<const float4*>(xrow +  96 + l * 4);
    float4 x4 = *reinterpret_cast<const float4*>(xrow + 128 + l * 4);
    float4 x5 = *reinterpret_cast<const float4*>(xrow + 160 + l * 4);
    float4 x6 = *reinterpret_cast<const float4*>(xrow + 192 + l * 4);
    float4 x7 = *reinterpret_cast<const float4*>(xrow + 224 + l * 4);

    int node = 0, pos = 0;
    float bcur = b_pred[0];
    const float* wrow = W_pred;

    #pragma unroll
    for (int lvl = 0; lvl < NLEVEL; ++lvl) {
        // Chunk A: rows 0..3 (reuse w0..w3 names so the allocator reuses
        // the same 16 registers for chunk B -> peak W residency 16 regs).
        float4 w0 = *reinterpret_cast<const float4*>(wrow +   0 + l * 4);
        float4 w1 = *reinterpret_cast<const float4*>(wrow +  32 + l * 4);
        float4 w2 = *reinterpret_cast<const float4*>(wrow +  64 + l * 4);
        float4 w3 = *reinterpret_cast<const float4*>(wrow +  96 + l * 4);

        // Children biases fetched before the sign resolves (off crit path).
        float bL = 0.f, bR = 0.f;
        if (lvl < NLEVEL - 1) {
            bL = b_pred[2 * node + 1];
            bR = b_pred[2 * node + 2];
        }

        float a0, a1, a2, a3;
        a0  = x0.x * w0.x; a1  = x0.y * w0.y; a2  = x0.z * w0.z; a3  = x0.w * w0.w;
        a0 += x1.x * w1.x; a1 += x1.y * w1.y; a2 += x1.z * w1.z; a3 += x1.w * w1.w;
        a0 += x2.x * w2.x; a1 += x2.y * w2.y; a2 += x2.z * w2.z; a3 += x2.w * w2.w;
        a0 += x3.x * w3.x; a1 += x3.y * w3.y; a2 += x3.z * w3.z; a3 += x3.w * w3.w;

        // Chunk B: rows 4..7 into the same registers.
        w0 = *reinterpret_cast<const float4*>(wrow + 128 + l * 4);
        w1 = *reinterpret_cast<const float4*>(wrow + 160 + l * 4);
        w2 = *reinterpret_cast<const float4*>(wrow + 192 + l * 4);
        w3 = *reinterpret_cast<const float4*>(wrow + 224 + l * 4);

        a0 += x4.x * w0.x; a1 += x4.y * w0.y; a2 += x4.z * w0.z; a3 += x4.w * w0.w;
        a0 += x5.x * w1.x; a1 += x5.y * w1.y; a2 += x5.z * w1.z; a3 += x5.w * w1.w;
        a0 += x6.x * w2.x; a1 += x6.y * w2.y; a2 += x6.z * w2.z; a3 += x6.w * w2.w;
        a0 += x7.x * w3.x; a1 += x7.y * w3.y; a2 += x7.z * w3.z; a3 += x7.w * w3.w;

        float z = group8_sum((a0 + a1) + (a2 + a3)) + bcur;

        int right;
        if (__builtin_expect(fabsf(z) >= EPS_TIE, 1))
            right = (z < 0.f) ? 1 : 0;
        else
            right = tree_sign_f64(x0, x1, x2, x3, x4, x5, x6, x7,
                                  wrow, bcur, l);   // group-uniform entry

        pos  = 2 * pos + right;
        node = 2 * node + 1 + right;
        if (lvl < NLEVEL - 1) {
            bcur = right ? bR : bL;
            wrow = W_pred + (size_t)node * IN_DIM;
        }
    }
    const int leaf = pos;  // in [0, 1024)

    // Epilogue: lane l covers classes {2l, 2l+1}; tables are L2-resident.
    float zx = W_or[(size_t)(2 * l)     * NLEAF + leaf];
    float zy = W_or[(size_t)(2 * l + 1) * NLEAF + leaf];
    float m  = group8_max(fmaxf(zx, zy));
    float ex = __expf(zx - m), ey = __expf(zy - m);
    float s  = group8_sum(ex + ey);
    // Per wave: addresses (base+g)*64B + l*8B -> contiguous 512B.
    *reinterpret_cast<float2*>(out + (size_t)sample * OUT_DIM + 2 * l) =
        make_float2(ex / s, ey / s);

    float dx = a_std[(size_t)(2 * l)     * NLEAF + leaf];
    float dy = a_std[(size_t)(2 * l + 1) * NLEAF + leaf];
    *reinterpret_cast<float2*>(out + (size_t)BATCH * OUT_DIM
                               + (size_t)sample * OUT_DIM + 2 * l) =
        make_float2(fminf(fmaxf(dx, -20.f), 2.f),
                    fminf(fmaxf(dy, -20.f), 2.f));
}

extern "C" void kernel_launch(void* const* d_in, const int* in_sizes, int n_in,
                              void* d_out, int out_size, void* d_ws, size_t ws_size,
                              hipStream_t stream) {
    const float* x      = (const float*)d_in[0];
    const float* W_pred = (const float*)d_in[1];
    const float* b_pred = (const float*)d_in[2];
    const float* W_or   = (const float*)d_in[3];
    const float* a_std  = (const float*)d_in[4];
    float* out = (float*)d_out;

    hipLaunchKernelGGL(dgt_kernel, dim3(BATCH / 32), dim3(256), 0, stream,
                       x, W_pred, b_pred, W_or, a_std, out);
}

// Round 11
// 43.093 us; speedup vs baseline: 1.0531x; 1.0531x over previous
//
#include <hip/hip_runtime.h>
#include <stdint.h>

// DGT forward, collapsed to a binary-tree descent on sign(pred_z[node]).
// R11: halve the dominant cost — W-row read traffic (10KB/sample, ~655MB of
// L2 reads) — by converting W_pred to packed bf16 once per launch (512KB in
// d_ws) and running the descent dot on bf16 W (+f32 x, f32 accum).
// Quantization error sigma ~1.1e-3 << EPS_TIE=0.02; when |z| < EPS_TIE the
// sign is recomputed in f64 from the ORIGINAL f32 W (exact vs numpy ref).
//
// Hard-learned laws (R1..R10):
//  - Structure footprint ~76 VGPR; capping VGPR below footprint spills
//    (WRITE_SIZE is the tell: must be ~8.4MB = output + ws).
//  - All clean structural variants land 37-39us -> shared limit = W traffic,
//    not per-chain latency/ILP. This round attacks bytes, not occupancy.
//  - ALL per-thread state in NAMED vars (runtime-indexed arrays spill).
//
// Shapes: x [65536,256] f32, W_pred [1023,256], b_pred [1023],
//         W_or [16,1024], action_stds [16,1024].
// d_out = [out (65536x16) | std (65536x16)] f32.

#define BATCH   65536
#define IN_DIM  256
#define NLEVEL  10
#define NLEAF   1024
#define OUT_DIM 16
#define EPS_TIE 0.02f
#define WB_U32  (1023 * 128)   // packed bf16 W: 128 u32 per row

#define DPP_QUAD_XOR1   0xB1   // quad_perm [1,0,3,2]  : lane ^1
#define DPP_QUAD_XOR2   0x4E   // quad_perm [2,3,0,1]  : lane ^2
#define DPP_HALF_MIRROR 0x141  // row_half_mirror      : lane l <-> 7-l

template <int CTRL>
__device__ __forceinline__ float dpp_xfer(float v) {
    return __int_as_float(__builtin_amdgcn_update_dpp(
        0, __float_as_int(v), CTRL, 0xf, 0xf, true));
}
__device__ __forceinline__ float group8_sum(float v) {
    v += dpp_xfer<DPP_QUAD_XOR1>(v);
    v += dpp_xfer<DPP_QUAD_XOR2>(v);
    v += dpp_xfer<DPP_HALF_MIRROR>(v);
    return v;
}
__device__ __forceinline__ float group8_max(float v) {
    v = fmaxf(v, dpp_xfer<DPP_QUAD_XOR1>(v));
    v = fmaxf(v, dpp_xfer<DPP_QUAD_XOR2>(v));
    v = fmaxf(v, dpp_xfer<DPP_HALF_MIRROR>(v));
    return v;
}

// bf16 unpack: element 2i sits in bits 15:0 (f32 = u<<16), 2i+1 in 31:16.
__device__ __forceinline__ float blo(uint32_t u) { return __uint_as_float(u << 16); }
__device__ __forceinline__ float bhi(uint32_t u) { return __uint_as_float(u & 0xffff0000u); }

// ---- prepass: W_pred f32 -> packed bf16 (RNE) in d_ws ----
__global__ __launch_bounds__(256) void dgt_prep(
    const float* __restrict__ W, uint32_t* __restrict__ Wb)
{
    int i = blockIdx.x * 256 + threadIdx.x;   // u32 index
    if (i < WB_U32) {
        uint32_t ua = __float_as_uint(W[2 * i]);
        uint32_t ub = __float_as_uint(W[2 * i + 1]);
        uint32_t ra = (ua + 0x7fffu + ((ua >> 16) & 1u)) >> 16;
        uint32_t rb = (ub + 0x7fffu + ((ub >> 16) & 1u)) >> 16;
        Wb[i] = ra | (rb << 16);
    }
}

// Rare exact-sign fallback (|z_bf16| < EPS_TIE): f64 dot on ORIGINAL f32 W.
// Group-uniform entry (z bitwise-uniform across the 8-lane group).
__device__ __forceinline__ int tree_sign_f64(
    float4 x0a, float4 x0b, float4 x1a, float4 x1b,
    float4 x2a, float4 x2b, float4 x3a, float4 x3b,
    const float* wrow, float bias, int l)
{
    double A0 = 0.0, A1 = 0.0, A2 = 0.0, A3 = 0.0;
#define ACC64(K, XA, XB)                                                     \
    {                                                                        \
        float4 wa = *reinterpret_cast<const float4*>(wrow + (K)*64 + l * 8); \
        float4 wb = *reinterpret_cast<const float4*>(wrow + (K)*64 + l * 8 + 4); \
        A0 += (double)XA.x * (double)wa.x; A1 += (double)XA.y * (double)wa.y; \
        A2 += (double)XA.z * (double)wa.z; A3 += (double)XA.w * (double)wa.w; \
        A0 += (double)XB.x * (double)wb.x; A1 += (double)XB.y * (double)wb.y; \
        A2 += (double)XB.z * (double)wb.z; A3 += (double)XB.w * (double)wb.w; \
    }
    ACC64(0, x0a, x0b) ACC64(1, x1a, x1b) ACC64(2, x2a, x2b) ACC64(3, x3a, x3b)
#undef ACC64
    double Z = (A0 + A1) + (A2 + A3);
    #pragma unroll
    for (int off = 4; off > 0; off >>= 1)   // xor involution: uniform result
        Z += __shfl_xor(Z, off, 64);
    Z += (double)bias;
    return (Z < 0.0) ? 1 : 0;
}

// ---- main: 256 threads = 4 waves; 8-lane groups, 8 samples/wave ----
__global__ __launch_bounds__(256, 2) void dgt_bf16(
    const float* __restrict__ x,
    const uint32_t* __restrict__ Wb,
    const float* __restrict__ W_pred,
    const float* __restrict__ b_pred,
    const float* __restrict__ W_or,
    const float* __restrict__ a_std,
    float* __restrict__ out)
{
    const int lane = threadIdx.x & 63;
    const int wid  = threadIdx.x >> 6;
    const int l    = lane & 7;           // lane within 8-group
    const int g    = lane >> 3;          // group (sample) within wave
    const int sample = blockIdx.x * 32 + wid * 8 + g;

    // x: lane l holds elements k*64 + l*8 + {0..7}, k=0..3 (8 float4s).
    const float* xrow = x + (size_t)sample * IN_DIM;
    float4 x0a = *reinterpret_cast<const float4*>(xrow +   0 + l * 8);
    float4 x0b = *reinterpret_cast<const float4*>(xrow +   4 + l * 8);
    float4 x1a = *reinterpret_cast<const float4*>(xrow +  64 + l * 8);
    float4 x1b = *reinterpret_cast<const float4*>(xrow +  68 + l * 8);
    float4 x2a = *reinterpret_cast<const float4*>(xrow + 128 + l * 8);
    float4 x2b = *reinterpret_cast<const float4*>(xrow + 132 + l * 8);
    float4 x3a = *reinterpret_cast<const float4*>(xrow + 192 + l * 8);
    float4 x3b = *reinterpret_cast<const float4*>(xrow + 196 + l * 8);

    int node = 0, pos = 0;
    float bcur = b_pred[0];

    #pragma unroll
    for (int lvl = 0; lvl < NLEVEL; ++lvl) {
        // bf16 row: 128 u32. Lane l loads uint4 at u32 offset k*32 + l*4
        // -> 128B coalesced per group-chunk; 4 loads (was 8 f32 loads).
        const uint32_t* wb = Wb + (size_t)node * 128;
        uint4 u0 = *reinterpret_cast<const uint4*>(wb +  0 + l * 4);
        uint4 u1 = *reinterpret_cast<const uint4*>(wb + 32 + l * 4);
        uint4 u2 = *reinterpret_cast<const uint4*>(wb + 64 + l * 4);
        uint4 u3 = *reinterpret_cast<const uint4*>(wb + 96 + l * 4);

        float bL = 0.f, bR = 0.f;
        if (lvl < NLEVEL - 1) {
            bL = b_pred[2 * node + 1];
            bR = b_pred[2 * node + 2];
        }

        float a0 = 0.f, a1 = 0.f, a2 = 0.f, a3 = 0.f;
#define ACCB(U, XA, XB)                                     \
        a0 += XA.x * blo(U.x); a1 += XA.y * bhi(U.x);       \
        a2 += XA.z * blo(U.y); a3 += XA.w * bhi(U.y);       \
        a0 += XB.x * blo(U.z); a1 += XB.y * bhi(U.z);       \
        a2 += XB.z * blo(U.w); a3 += XB.w * bhi(U.w);
        ACCB(u0, x0a, x0b)
        ACCB(u1, x1a, x1b)
        ACCB(u2, x2a, x2b)
        ACCB(u3, x3a, x3b)
#undef ACCB
        float z = group8_sum((a0 + a1) + (a2 + a3)) + bcur;

        int right;
        if (__builtin_expect(fabsf(z) >= EPS_TIE, 1))
            right = (z < 0.f) ? 1 : 0;
        else
            right = tree_sign_f64(x0a, x0b, x1a, x1b, x2a, x2b, x3a, x3b,
                                  W_pred + (size_t)node * IN_DIM, bcur, l);

        pos  = 2 * pos + right;
        node = 2 * node + 1 + right;
        if (lvl < NLEVEL - 1) bcur = right ? bR : bL;
    }
    const int leaf = pos;  // in [0, 1024)

    // Epilogue: lane l covers classes {2l, 2l+1}; tables are L2-resident.
    float zx = W_or[(size_t)(2 * l)     * NLEAF + leaf];
    float zy = W_or[(size_t)(2 * l + 1) * NLEAF + leaf];
    float m  = group8_max(fmaxf(zx, zy));
    float ex = __expf(zx - m), ey = __expf(zy - m);
    float s  = group8_sum(ex + ey);
    *reinterpret_cast<float2*>(out + (size_t)sample * OUT_DIM + 2 * l) =
        make_float2(ex / s, ey / s);

    float dx = a_std[(size_t)(2 * l)     * NLEAF + leaf];
    float dy = a_std[(size_t)(2 * l + 1) * NLEAF + leaf];
    *reinterpret_cast<float2*>(out + (size_t)BATCH * OUT_DIM
                               + (size_t)sample * OUT_DIM + 2 * l) =
        make_float2(fminf(fmaxf(dx, -20.f), 2.f),
                    fminf(fmaxf(dy, -20.f), 2.f));
}

// ---- fallback (ws too small): R8 kernel, f32 W direct ----
__device__ __forceinline__ int tree_sign_f64_r8(
    float4 x0, float4 x1, float4 x2, float4 x3,
    float4 x4, float4 x5, float4 x6, float4 x7,
    const float* wrow, float bias, int l)
{
    double A0 = 0.0, A1 = 0.0, A2 = 0.0, A3 = 0.0;
#define ACC64(K, XV)                                                        \
    {                                                                       \
        float4 w = *reinterpret_cast<const float4*>(wrow + (K)*32 + l * 4); \
        A0 += (double)XV.x * (double)w.x; A1 += (double)XV.y * (double)w.y; \
        A2 += (double)XV.z * (double)w.z; A3 += (double)XV.w * (double)w.w; \
    }
    ACC64(0, x0) ACC64(1, x1) ACC64(2, x2) ACC64(3, x3)
    ACC64(4, x4) ACC64(5, x5) ACC64(6, x6) ACC64(7, x7)
#undef ACC64
    double Z = (A0 + A1) + (A2 + A3);
    #pragma unroll
    for (int off = 4; off > 0; off >>= 1)
        Z += __shfl_xor(Z, off, 64);
    Z += (double)bias;
    return (Z < 0.0) ? 1 : 0;
}

__global__ __launch_bounds__(256, 2) void dgt_f32(
    const float* __restrict__ x,
    const float* __restrict__ W_pred,
    const float* __restrict__ b_pred,
    const float* __restrict__ W_or,
    const float* __restrict__ a_std,
    float* __restrict__ out)
{
    const int lane = threadIdx.x & 63;
    const int wid  = threadIdx.x >> 6;
    const int l    = lane & 7;
    const int g    = lane >> 3;
    const int sample = blockIdx.x * 32 + wid * 8 + g;

    const float* xrow = x + (size_t)sample * IN_DIM;
    float4 x0 = *reinterpret_cast<const float4*>(xrow +   0 + l * 4);
    float4 x1 = *reinterpret_cast<const float4*>(xrow +  32 + l * 4);
    float4 x2 = *reinterpret_cast<const float4*>(xrow +  64 + l * 4);
    float4 x3 = *reinterpret_cast<const float4*>(xrow +  96 + l * 4);
    float4 x4 = *reinterpret_cast<const float4*>(xrow + 128 + l * 4);
    float4 x5 = *reinterpret_cast<const float4*>(xrow + 160 + l * 4);
    float4 x6 = *reinterpret_cast<const float4*>(xrow + 192 + l * 4);
    float4 x7 = *reinterpret_cast<const float4*>(xrow + 224 + l * 4);

    int node = 0, pos = 0;
    float bcur = b_pred[0];
    const float* wrow = W_pred;

    #pragma unroll
    for (int lvl = 0; lvl < NLEVEL; ++lvl) {
        float4 w0 = *reinterpret_cast<const float4*>(wrow +   0 + l * 4);
        float4 w1 = *reinterpret_cast<const float4*>(wrow +  32 + l * 4);
        float4 w2 = *reinterpret_cast<const float4*>(wrow +  64 + l * 4);
        float4 w3 = *reinterpret_cast<const float4*>(wrow +  96 + l * 4);
        float4 w4 = *reinterpret_cast<const float4*>(wrow + 128 + l * 4);
        float4 w5 = *reinterpret_cast<const float4*>(wrow + 160 + l * 4);
        float4 w6 = *reinterpret_cast<const float4*>(wrow + 192 + l * 4);
        float4 w7 = *reinterpret_cast<const float4*>(wrow + 224 + l * 4);

        float bL = 0.f, bR = 0.f;
        if (lvl < NLEVEL - 1) {
            bL = b_pred[2 * node + 1];
            bR = b_pred[2 * node + 2];
        }

        float a0, a1, a2, a3;
        a0  = x0.x * w0.x; a1  = x0.y * w0.y; a2  = x0.z * w0.z; a3  = x0.w * w0.w;
        a0 += x1.x * w1.x; a1 += x1.y * w1.y; a2 += x1.z * w1.z; a3 += x1.w * w1.w;
        a0 += x2.x * w2.x; a1 += x2.y * w2.y; a2 += x2.z * w2.z; a3 += x2.w * w2.w;
        a0 += x3.x * w3.x; a1 += x3.y * w3.y; a2 += x3.z * w3.z; a3 += x3.w * w3.w;
        a0 += x4.x * w4.x; a1 += x4.y * w4.y; a2 += x4.z * w4.z; a3 += x4.w * w4.w;
        a0 += x5.x * w5.x; a1 += x5.y * w5.y; a2 += x5.z * w5.z; a3 += x5.w * w5.w;
        a0 += x6.x * w6.x; a1 += x6.y * w6.y; a2 += x6.z * w6.z; a3 += x6.w * w6.w;
        a0 += x7.x * w7.x; a1 += x7.y * w7.y; a2 += x7.z * w7.z; a3 += x7.w * w7.w;
        float z = group8_sum((a0 + a1) + (a2 + a3)) + bcur;

        int right;
        if (__builtin_expect(fabsf(z) >= 1e-3f, 1))
            right = (z < 0.f) ? 1 : 0;
        else
            right = tree_sign_f64_r8(x0, x1, x2, x3, x4, x5, x6, x7,
                                     wrow, bcur, l);

        pos  = 2 * pos + right;
        node = 2 * node + 1 + right;
        if (lvl < NLEVEL - 1) {
            bcur = right ? bR : bL;
            wrow = W_pred + (size_t)node * IN_DIM;
        }
    }
    const int leaf = pos;

    float zx = W_or[(size_t)(2 * l)     * NLEAF + leaf];
    float zy = W_or[(size_t)(2 * l + 1) * NLEAF + leaf];
    float m  = group8_max(fmaxf(zx, zy));
    float ex = __expf(zx - m), ey = __expf(zy - m);
    float s  = group8_sum(ex + ey);
    *reinterpret_cast<float2*>(out + (size_t)sample * OUT_DIM + 2 * l) =
        make_float2(ex / s, ey / s);

    float dx = a_std[(size_t)(2 * l)     * NLEAF + leaf];
    float dy = a_std[(size_t)(2 * l + 1) * NLEAF + leaf];
    *reinterpret_cast<float2*>(out + (size_t)BATCH * OUT_DIM
                               + (size_t)sample * OUT_DIM + 2 * l) =
        make_float2(fminf(fmaxf(dx, -20.f), 2.f),
                    fminf(fmaxf(dy, -20.f), 2.f));
}

extern "C" void kernel_launch(void* const* d_in, const int* in_sizes, int n_in,
                              void* d_out, int out_size, void* d_ws, size_t ws_size,
                              hipStream_t stream) {
    const float* x      = (const float*)d_in[0];
    const float* W_pred = (const float*)d_in[1];
    const float* b_pred = (const float*)d_in[2];
    const float* W_or   = (const float*)d_in[3];
    const float* a_std  = (const float*)d_in[4];
    float* out = (float*)d_out;

    if (ws_size >= (size_t)WB_U32 * 4) {
        uint32_t* Wb = (uint32_t*)d_ws;
        hipLaunchKernelGGL(dgt_prep, dim3((WB_U32 + 255) / 256), dim3(256),
                           0, stream, W_pred, Wb);
        hipLaunchKernelGGL(dgt_bf16, dim3(BATCH / 32), dim3(256), 0, stream,
                           x, Wb, W_pred, b_pred, W_or, a_std, out);
    } else {
        hipLaunchKernelGGL(dgt_f32, dim3(BATCH / 32), dim3(256), 0, stream,
                           x, W_pred, b_pred, W_or, a_std, out);
    }
}